// Round 4
// baseline (1233.460 us; speedup 1.0000x reference)
//
#include <hip/hip_runtime.h>

// RNNDecoderP round 4: round-3 structure (one sequence per HALF-WAVE; full K=32
// per-lane dots, no cross-lane partial sums) with the MLP reduction done via
// __shfl_xor butterfly instead of DPP row_bcast:15 (0x142) — that DPP ctrl was
// removed from CDNA at gfx90a and is illegal on gfx950 (round-3 SIGABRT).
// xor masks {1,2,4,8,16} never cross the 32-lane half boundary, so each
// half-wave reduces its own band independently.

typedef float v2f __attribute__((ext_vector_type(2)));

constexpr int Bn  = 256;
constexpr int Tn  = 2048;
constexpr int Dn  = 64;
constexpr int DBn = 32;
constexpr int Ln  = 2;
constexpr int Gn  = 96;

#if __has_builtin(__builtin_amdgcn_exp2f)
__device__ __forceinline__ float exp2_fast(float x) { return __builtin_amdgcn_exp2f(x); }
#else
__device__ __forceinline__ float exp2_fast(float x) { return exp2f(x); }
#endif
#if __has_builtin(__builtin_amdgcn_rcpf)
__device__ __forceinline__ float rcp_fast(float x) { return __builtin_amdgcn_rcpf(x); }
#else
__device__ __forceinline__ float rcp_fast(float x) { return 1.0f / x; }
#endif

__device__ __forceinline__ float sigmoid_f(float x) {
  return rcp_fast(1.0f + exp2_fast(-1.4426950408889634f * x));
}
__device__ __forceinline__ float tanh_f(float x) {
  return 1.0f - 2.0f * rcp_fast(1.0f + exp2_fast(2.8853900817779268f * x));
}

// full 32-dot, single pk-chain (off-chain dots)
__device__ __forceinline__ float dot16(const v2f* __restrict__ w, const v2f* __restrict__ h) {
  v2f a = {0.0f, 0.0f};
  #pragma unroll
  for (int q = 0; q < 16; ++q) a = __builtin_elementwise_fma(w[q], h[q], a);
  return a.x + a.y;
}
// full 32-dot, two pk-chains (on-chain dots: half the dependent latency)
__device__ __forceinline__ float dot16b(const v2f* __restrict__ w, const v2f* __restrict__ h) {
  v2f a = {0.0f, 0.0f}, b = {0.0f, 0.0f};
  #pragma unroll
  for (int q = 0; q < 8; ++q) {
    a = __builtin_elementwise_fma(w[q], h[q], a);
    b = __builtin_elementwise_fma(w[q + 8], h[q + 8], b);
  }
  a = a + b;
  return a.x + a.y;
}

__device__ __forceinline__ void ldrow(const float* __restrict__ p, v2f* d) {
  #pragma unroll
  for (int q = 0; q < 8; ++q) {
    float4 a = ((const float4*)p)[q];
    d[2*q] = (v2f){a.x, a.y}; d[2*q+1] = (v2f){a.z, a.w};
  }
}
__device__ __forceinline__ void ldlds(const float* p, v2f* d) {
  #pragma unroll
  for (int q = 0; q < 8; ++q) {
    float4 a = ((const float4*)p)[q];
    d[2*q] = (v2f){a.x, a.y}; d[2*q+1] = (v2f){a.z, a.w};
  }
}

// sum within each 32-lane half; valid in all lanes (xor masks < 32 stay in-half)
__device__ __forceinline__ float red32(float x) {
  x += __shfl_xor(x, 1, 64);
  x += __shfl_xor(x, 2, 64);
  x += __shfl_xor(x, 4, 64);
  x += __shfl_xor(x, 8, 64);
  x += __shfl_xor(x, 16, 64);
  return x;
}

__global__ __launch_bounds__(64, 1)
void rnn_decoder(const int* __restrict__ band_ids, const float* __restrict__ dtime,
                 const float* __restrict__ z_last, const float* __restrict__ projW,
                 const float* __restrict__ projB, const float* __restrict__ Wih,
                 const float* __restrict__ Whh, const float* __restrict__ bih,
                 const float* __restrict__ bhh, const float* __restrict__ mW1,
                 const float* __restrict__ mb1, const float* __restrict__ mW2,
                 const float* __restrict__ mb2, float* __restrict__ out) {
  const int b    = blockIdx.x;
  const int L    = threadIdx.x;   // 0..63
  const int i    = L & 31;        // owned h-element / gate row
  const int half = L >> 5;        // which band this half-wave runs
  const int kb   = half;

  __shared__ __align__(16) float yd[2][Tn];   // per-band compacted dtime -> outputs
  __shared__ __align__(16) float hsh1[2][DBn];
  __shared__ __align__(16) float hsh2[2][DBn];
  __shared__ __align__(16) float xb[2][DBn];
  __shared__ __align__(16) float xs[2][DBn];

  // ---------------- stable compaction (per half, 2 chunks of 1024) ----------------
  const int*   brow = band_ids + b * Tn;
  const float* drow = dtime    + b * Tn;
  int base = 0;
  #pragma unroll
  for (int c = 0; c < 2; ++c) {
    int4 bc[8];
    int cnt = 0;
    #pragma unroll
    for (int it = 0; it < 8; ++it) {
      bc[it] = ((const int4*)(brow + c * 1024 + i * 32))[it];
      cnt += (bc[it].x == kb) + (bc[it].y == kb) + (bc[it].z == kb) + (bc[it].w == kb);
    }
    int incl = cnt;
    #pragma unroll
    for (int dlt = 1; dlt < 32; dlt <<= 1) {
      int v = __shfl_up(incl, dlt, 64);
      if (i >= dlt) incl += v;
    }
    int off = base + incl - cnt;
    base += __shfl(incl, half * 32 + 31, 64);
    #pragma unroll
    for (int it = 0; it < 8; ++it) {
      float4 dd = ((const float4*)(drow + c * 1024 + i * 32))[it];
      if (bc[it].x == kb) yd[half][off++] = dd.x;
      if (bc[it].y == kb) yd[half][off++] = dd.y;
      if (bc[it].z == kb) yd[half][off++] = dd.z;
      if (bc[it].w == kb) yd[half][off++] = dd.w;
    }
  }
  const int nh   = base;
  const int nmax = max(nh, __shfl_xor(nh, 32, 64));

  // ---------------- projection fold: x_t = xb + d_t * xs ----------------
  {
    const float* pw = projW + kb * (Dn + 1) * DBn + i;
    const float* zl = z_last + b * Dn;
    float acc = 0.0f;
    #pragma unroll 8
    for (int k = 0; k < Dn; ++k) acc = fmaf(zl[k], pw[k * DBn], acc);
    xb[half][i] = acc + projB[kb * DBn + i];
    xs[half][i] = pw[Dn * DBn];
  }
  __syncthreads();

  // ---------------- per-gate affine constants for layer-1 input ----------------
  const float* wih1  = Wih + (kb * Ln + 0) * Gn * DBn;
  const float* bih1p = bih + (kb * Ln + 0) * Gn;
  const float* bhh1p = bhh + (kb * Ln + 0) * Gn;
  const float* bih2p = bih + (kb * Ln + 1) * Gn;
  const float* bhh2p = bhh + (kb * Ln + 1) * Gn;
  float gb_r = 0, gb_z = 0, gb_n = 0, gs_r = 0, gs_z = 0, gs_n = 0;
  {
    const float* wr = wih1 + (     i) * DBn;
    const float* wz = wih1 + (32 + i) * DBn;
    const float* wn = wih1 + (64 + i) * DBn;
    #pragma unroll 4
    for (int j = 0; j < DBn; ++j) {
      float xbv = xb[half][j], xsv = xs[half][j];
      gb_r = fmaf(wr[j], xbv, gb_r);  gs_r = fmaf(wr[j], xsv, gs_r);
      gb_z = fmaf(wz[j], xbv, gb_z);  gs_z = fmaf(wz[j], xsv, gs_z);
      gb_n = fmaf(wn[j], xbv, gb_n);  gs_n = fmaf(wn[j], xsv, gs_n);
    }
  }
  gb_r += bih1p[i]      + bhh1p[i];        // r/z: both biases additive
  gb_z += bih1p[32 + i] + bhh1p[32 + i];
  gb_n += bih1p[64 + i];                   // n: bhh inside r*(.)
  const float bhh1n = bhh1p[64 + i];
  const float c2r   = bih2p[i]      + bhh2p[i];
  const float c2z   = bih2p[32 + i] + bhh2p[32 + i];
  const float bih2n = bih2p[64 + i];
  const float bhh2n = bhh2p[64 + i];
  const float mb1i  = mb1[kb * DBn + i];
  const float mW2i  = mW2[kb * DBn + i];
  const float mb2v  = mb2[kb];

  // ---------------- register-resident full gate rows ----------------
  v2f w1r[16], w1z[16], w1n[16];   // Whh layer1 rows i / 32+i / 64+i
  v2f u2r[16], u2z[16], u2n[16];   // Wih layer2
  v2f w2r[16], w2z[16], w2n[16];   // Whh layer2
  v2f m1[16];                      // mW1 column i
  {
    const float* whh1 = Whh + (kb * Ln + 0) * Gn * DBn;
    const float* wih2 = Wih + (kb * Ln + 1) * Gn * DBn;
    const float* whh2 = Whh + (kb * Ln + 1) * Gn * DBn;
    ldrow(whh1 + (     i) * DBn, w1r);
    ldrow(whh1 + (32 + i) * DBn, w1z);
    ldrow(whh1 + (64 + i) * DBn, w1n);
    ldrow(wih2 + (     i) * DBn, u2r);
    ldrow(wih2 + (32 + i) * DBn, u2z);
    ldrow(wih2 + (64 + i) * DBn, u2n);
    ldrow(whh2 + (     i) * DBn, w2r);
    ldrow(whh2 + (32 + i) * DBn, w2z);
    ldrow(whh2 + (64 + i) * DBn, w2n);
    #pragma unroll
    for (int q = 0; q < 16; ++q)
      m1[q] = (v2f){ mW1[(kb * DBn + 2*q)     * DBn + i],
                     mW1[(kb * DBn + 2*q + 1) * DBn + i] };
  }

  // ---------------- scan state ----------------
  hsh2[half][i] = 0.0f;
  v2f h1all[16];
  #pragma unroll
  for (int q = 0; q < 16; ++q) h1all[q] = (v2f){0.0f, 0.0f};
  float h1self = 0.0f, h2self = 0.0f;
  __syncthreads();

  // ---------------- sequential scan ----------------
  for (int t = 0; t < nmax; ++t) {
    float d = yd[half][t];           // prefetch early (off-chain)
    v2f h2all[16];
    ldlds(&hsh2[half][0], h2all);    // h2_{t-1}

    // deferred MLP head for step t-1 (off-chain)
    float s = dot16(m1, h2all) + mb1i;
    s = fmaxf(s, 0.0f) * mW2i;
    s = red32(s) + mb2v;
    if (t > 0 && i == 31) yd[half][t - 1] = s;

    // L2 recurrent gates from h2_{t-1} (off-chain, consumed late)
    float cr = dot16(w2r, h2all) + c2r;
    float cz = dot16(w2z, h2all) + c2z;
    float cn = dot16(w2n, h2all) + bhh2n;

    // ---- layer 1 (loop-carried chain) ----
    float ar = dot16b(w1r, h1all);
    float az = dot16b(w1z, h1all);
    float an = dot16b(w1n, h1all);
    float r1  = sigmoid_f(fmaf(d, gs_r, gb_r) + ar);
    float z1  = sigmoid_f(fmaf(d, gs_z, gb_z) + az);
    float n1  = tanh_f(fmaf(d, gs_n, gb_n) + r1 * (an + bhh1n));
    float h1n = fmaf(z1, h1self - n1, n1);
    h1self = (t < nh) ? h1n : h1self;     // frozen past this band's length
    hsh1[half][i] = h1self;
    __builtin_amdgcn_wave_barrier();
    ldlds(&hsh1[half][0], h1all);

    // ---- layer 2 ----
    float br = dot16b(u2r, h1all);
    float bz = dot16b(u2z, h1all);
    float bn = dot16b(u2n, h1all) + bih2n;
    float r2  = sigmoid_f(br + cr);
    float z2  = sigmoid_f(bz + cz);
    float n2  = tanh_f(bn + r2 * cn);
    float h2n = fmaf(z2, h2self - n2, n2);
    h2self = (t < nh) ? h2n : h2self;
    hsh2[half][i] = h2self;
    __builtin_amdgcn_wave_barrier();
  }

  // ---------------- epilogue: MLP for the final step ----------------
  {
    v2f h2all[16];
    ldlds(&hsh2[half][0], h2all);
    float s = dot16(m1, h2all) + mb1i;
    s = fmaxf(s, 0.0f) * mW2i;
    s = red32(s) + mb2v;
    if (nmax > 0 && i == 31) yd[half][nmax - 1] = s;
    // s is valid in all lanes of each half; the frozen half's s == its ylast too
    for (int t = nmax + i; t < Tn; t += 32) yd[half][t] = s;
  }
  __syncthreads();

  // ---------------- coalesced store (each half stores its band's row) ----------------
  float* orow = out + (half * Bn + b) * Tn;
  #pragma unroll
  for (int q = 0; q < 16; ++q) {
    const int idx = (q * 32 + i) * 4;
    *(float4*)(orow + idx) = *(const float4*)&yd[half][idx];
  }
}

extern "C" void kernel_launch(void* const* d_in, const int* in_sizes, int n_in,
                              void* d_out, int out_size, void* d_ws, size_t ws_size,
                              hipStream_t stream) {
  const int*   band_ids = (const int*)  d_in[0];
  const float* dtime    = (const float*)d_in[1];
  const float* z_last   = (const float*)d_in[2];
  const float* projW    = (const float*)d_in[3];
  const float* projB    = (const float*)d_in[4];
  const float* Wih      = (const float*)d_in[5];
  const float* Whh      = (const float*)d_in[6];
  const float* bihp     = (const float*)d_in[7];
  const float* bhhp     = (const float*)d_in[8];
  const float* mW1      = (const float*)d_in[9];
  const float* mb1      = (const float*)d_in[10];
  const float* mW2      = (const float*)d_in[11];
  const float* mb2      = (const float*)d_in[12];
  float* out = (float*)d_out;
  rnn_decoder<<<dim3(Bn), dim3(64), 0, stream>>>(
      band_ids, dtime, z_last, projW, projB, Wih, Whh, bihp, bhhp,
      mW1, mb1, mW2, mb2, out);
}

// Round 5
// 675.241 us; speedup vs baseline: 1.8267x; 1.8267x over previous
//
#include <hip/hip_runtime.h>

// RNNDecoderP round 5: round-2 register layout (one wave per (row,band), 2 lanes
// per element, 16-wide half-dots + one shfl_xor(32) combine — fits the compiler's
// ~200-VGPR comfort zone; round 4 proved full-K spills and reloads on-chain).
// New: cross-layer software pipelining. The only loop-carried cycle is layer 1's
// recurrence; layer 2 runs at lag-1 (uses h1_{t-1}, h2_{t-2} already in regs) and
// the MLP head at lag-2 — both placed between the h1 LDS write and read so their
// ~300 cycles of independent VALU cover the roundtrip latency.

typedef float v2f __attribute__((ext_vector_type(2)));

constexpr int Bn  = 256;
constexpr int Tn  = 2048;
constexpr int Dn  = 64;
constexpr int DBn = 32;
constexpr int Ln  = 2;
constexpr int Gn  = 96;

#if __has_builtin(__builtin_amdgcn_exp2f)
__device__ __forceinline__ float exp2_fast(float x) { return __builtin_amdgcn_exp2f(x); }
#else
__device__ __forceinline__ float exp2_fast(float x) { return exp2f(x); }
#endif
#if __has_builtin(__builtin_amdgcn_rcpf)
__device__ __forceinline__ float rcp_fast(float x) { return __builtin_amdgcn_rcpf(x); }
#else
__device__ __forceinline__ float rcp_fast(float x) { return 1.0f / x; }
#endif

__device__ __forceinline__ float sigmoid_f(float x) {
  return rcp_fast(1.0f + exp2_fast(-1.4426950408889634f * x));
}
__device__ __forceinline__ float tanh_f(float x) {
  return 1.0f - 2.0f * rcp_fast(1.0f + exp2_fast(2.8853900817779268f * x));
}

__device__ __forceinline__ float dot8(const v2f* __restrict__ w, const v2f* __restrict__ h) {
  v2f a = {0.0f, 0.0f};
  #pragma unroll
  for (int q = 0; q < 8; ++q) a = __builtin_elementwise_fma(w[q], h[q], a);
  return a.x + a.y;
}

__device__ __forceinline__ void ldlds(const float* p, v2f* d) {
  #pragma unroll
  for (int q = 0; q < 4; ++q) {
    float4 a = ((const float4*)p)[q];
    d[2*q] = (v2f){a.x, a.y}; d[2*q+1] = (v2f){a.z, a.w};
  }
}

__global__ __launch_bounds__(64, 1)
void rnn_decoder(const int* __restrict__ band_ids, const float* __restrict__ dtime,
                 const float* __restrict__ z_last, const float* __restrict__ projW,
                 const float* __restrict__ projB, const float* __restrict__ Wih,
                 const float* __restrict__ Whh, const float* __restrict__ bih,
                 const float* __restrict__ bhh, const float* __restrict__ mW1,
                 const float* __restrict__ mb1, const float* __restrict__ mW2,
                 const float* __restrict__ mb2, float* __restrict__ out) {
  const int b    = blockIdx.x >> 1;
  const int kb   = blockIdx.x & 1;
  const int L    = threadIdx.x;   // 0..63
  const int i    = L & 31;        // owned gate/element index
  const int half = L >> 5;        // which 16-wide half of the dot
  const int koff = half * 16;

  __shared__ __align__(16) float yd[Tn + 1];      // compacted dtime; y after batch reduce
  __shared__ __align__(16) float yc[8 * (Tn + 1)]; // 8 MLP partials per step; slot Tn = ylast
  __shared__ __align__(16) float hsh1[DBn];
  __shared__ __align__(16) float hsh2[DBn];
  __shared__ __align__(16) float xb[DBn];
  __shared__ __align__(16) float xs[DBn];

  // ---------------- stable compaction of this band's dtime ----------------
  const int*   brow = band_ids + b * Tn;
  const float* drow = dtime    + b * Tn;
  int cnt = 0;
  int4 bcache[8];
  #pragma unroll
  for (int it = 0; it < 8; ++it) {
    int4 v = ((const int4*)(brow + L * 32))[it];
    bcache[it] = v;
    cnt += (v.x == kb) + (v.y == kb) + (v.z == kb) + (v.w == kb);
  }
  int incl = cnt;
  #pragma unroll
  for (int dlt = 1; dlt < 64; dlt <<= 1) {
    int v = __shfl_up(incl, dlt, 64);
    if (L >= dlt) incl += v;
  }
  int off = incl - cnt;
  const int n = __shfl(incl, 63, 64);
  #pragma unroll
  for (int it = 0; it < 8; ++it) {
    int4   v  = bcache[it];
    float4 dd = ((const float4*)(drow + L * 32))[it];
    if (v.x == kb) yd[off++] = dd.x;
    if (v.y == kb) yd[off++] = dd.y;
    if (v.z == kb) yd[off++] = dd.z;
    if (v.w == kb) yd[off++] = dd.w;
  }

  // ---------------- projection fold: x_t = xb + d_t * xs ----------------
  {
    const float* pw = projW + (kb * (Dn + 1)) * DBn + i;
    const float* zl = z_last + b * Dn;
    float acc = 0.0f;
    #pragma unroll 8
    for (int k = 0; k < Dn; ++k) acc = fmaf(zl[k], pw[k * DBn], acc);
    xb[i] = acc + projB[kb * DBn + i];
    xs[i] = pw[Dn * DBn];
  }
  __syncthreads();

  // ---------------- register-resident weights (half-rows as v2f) ----------------
  v2f w1r[8], w1z[8], w1n[8];   // Whh layer1
  v2f u2r[8], u2z[8], u2n[8];   // Wih layer2
  v2f w2r[8], w2z[8], w2n[8];   // Whh layer2
  v2f m1p[8];                   // mW1 half-column i
  {
    const float* whh1 = Whh + ((kb * Ln + 0) * Gn) * DBn;
    const float* wih2 = Wih + ((kb * Ln + 1) * Gn) * DBn;
    const float* whh2 = Whh + ((kb * Ln + 1) * Gn) * DBn;
    #pragma unroll
    for (int q = 0; q < 4; ++q) {
      float4 a;
      a = ((const float4*)(whh1 + (     i) * DBn + koff))[q];
      w1r[2*q] = (v2f){a.x, a.y}; w1r[2*q+1] = (v2f){a.z, a.w};
      a = ((const float4*)(whh1 + (32 + i) * DBn + koff))[q];
      w1z[2*q] = (v2f){a.x, a.y}; w1z[2*q+1] = (v2f){a.z, a.w};
      a = ((const float4*)(whh1 + (64 + i) * DBn + koff))[q];
      w1n[2*q] = (v2f){a.x, a.y}; w1n[2*q+1] = (v2f){a.z, a.w};
      a = ((const float4*)(wih2 + (     i) * DBn + koff))[q];
      u2r[2*q] = (v2f){a.x, a.y}; u2r[2*q+1] = (v2f){a.z, a.w};
      a = ((const float4*)(wih2 + (32 + i) * DBn + koff))[q];
      u2z[2*q] = (v2f){a.x, a.y}; u2z[2*q+1] = (v2f){a.z, a.w};
      a = ((const float4*)(wih2 + (64 + i) * DBn + koff))[q];
      u2n[2*q] = (v2f){a.x, a.y}; u2n[2*q+1] = (v2f){a.z, a.w};
      a = ((const float4*)(whh2 + (     i) * DBn + koff))[q];
      w2r[2*q] = (v2f){a.x, a.y}; w2r[2*q+1] = (v2f){a.z, a.w};
      a = ((const float4*)(whh2 + (32 + i) * DBn + koff))[q];
      w2z[2*q] = (v2f){a.x, a.y}; w2z[2*q+1] = (v2f){a.z, a.w};
      a = ((const float4*)(whh2 + (64 + i) * DBn + koff))[q];
      w2n[2*q] = (v2f){a.x, a.y}; w2n[2*q+1] = (v2f){a.z, a.w};
    }
    #pragma unroll
    for (int q = 0; q < 8; ++q)
      m1p[q] = (v2f){ mW1[(kb * DBn + koff + 2*q)     * DBn + i],
                      mW1[(kb * DBn + koff + 2*q + 1) * DBn + i] };
  }

  // ---------------- per-gate affine constants for layer-1 input ----------------
  const float* wih1  = Wih + ((kb * Ln + 0) * Gn) * DBn;
  const float* bih1p = bih + (kb * Ln + 0) * Gn;
  const float* bhh1p = bhh + (kb * Ln + 0) * Gn;
  const float* bih2p = bih + (kb * Ln + 1) * Gn;
  const float* bhh2p = bhh + (kb * Ln + 1) * Gn;
  float gb_r = 0, gb_z = 0, gb_n = 0, gs_r = 0, gs_z = 0, gs_n = 0;
  #pragma unroll 4
  for (int j = 0; j < DBn; ++j) {
    float xbv = xb[j], xsv = xs[j];
    float wr = wih1[(     i) * DBn + j];
    float wz = wih1[(32 + i) * DBn + j];
    float wn = wih1[(64 + i) * DBn + j];
    gb_r = fmaf(wr, xbv, gb_r);  gs_r = fmaf(wr, xsv, gs_r);
    gb_z = fmaf(wz, xbv, gb_z);  gs_z = fmaf(wz, xsv, gs_z);
    gb_n = fmaf(wn, xbv, gb_n);  gs_n = fmaf(wn, xsv, gs_n);
  }
  gb_r += bih1p[i]      + bhh1p[i];        // r/z: both biases additive
  gb_z += bih1p[32 + i] + bhh1p[32 + i];
  gb_n += bih1p[64 + i];                   // n: bhh inside r*(.)
  const float bhh1n = bhh1p[64 + i];
  const float c2r   = bih2p[i]      + bhh2p[i];
  const float c2z   = bih2p[32 + i] + bhh2p[32 + i];
  const float bih2n = bih2p[64 + i];
  const float bhh2n = bhh2p[64 + i];
  const float mb1i  = mb1[kb * DBn + i];
  const float mW2i  = mW2[kb * DBn + i];
  const float mb2v  = mb2[kb];

  // ---------------- scan state (pipelined: L2 at lag-1, MLP at lag-2) ----------------
  v2f h1a[8], h2a[8];            // h1_{t-1} half, h2_{t-2} half
  #pragma unroll
  for (int q = 0; q < 8; ++q) { h1a[q] = (v2f){0.0f, 0.0f}; h2a[q] = (v2f){0.0f, 0.0f}; }
  float h1self = 0.0f, h2self = 0.0f;
  float d = yd[0];

  // ---------------- sequential scan ----------------
  for (int t = 0; t < n; ++t) {
    // ---- layer 1 step t (the only loop-carried cycle) ----
    float ar = dot8(w1r, h1a);
    float az = dot8(w1z, h1a);
    float an = dot8(w1n, h1a);
    ar += __shfl_xor(ar, 32, 64);
    az += __shfl_xor(az, 32, 64);
    an += __shfl_xor(an, 32, 64);
    float r1 = sigmoid_f(fmaf(d, gs_r, gb_r) + ar);
    float z1 = sigmoid_f(fmaf(d, gs_z, gb_z) + az);
    float n1 = tanh_f(fmaf(d, gs_n, gb_n) + r1 * (an + bhh1n));
    h1self = fmaf(z1, h1self - n1, n1);
    hsh1[i] = h1self;                       // h1_t (write covered by L2/MLP below)

    // ---- layer 2 step t-1 (off-chain: h1_{t-1}, h2_{t-2} already in regs) ----
    float br = dot8(u2r, h1a);
    float bz = dot8(u2z, h1a);
    float bn = dot8(u2n, h1a);
    float cr = dot8(w2r, h2a);
    float cz = dot8(w2z, h2a);
    float cn = dot8(w2n, h2a);
    br += __shfl_xor(br, 32, 64);
    bz += __shfl_xor(bz, 32, 64);
    bn += __shfl_xor(bn, 32, 64);
    cr += __shfl_xor(cr, 32, 64);
    cz += __shfl_xor(cz, 32, 64);
    cn += __shfl_xor(cn, 32, 64);
    float r2 = sigmoid_f(br + cr + c2r);
    float z2 = sigmoid_f(bz + cz + c2z);
    float n2 = tanh_f((bn + bih2n) + r2 * (cn + bhh2n));
    float h2n = fmaf(z2, h2self - n2, n2);
    if (t >= 1) h2self = h2n;               // step t-1 exists only for t>=1
    hsh2[i] = h2self;                       // h2_{t-1}

    // ---- MLP head step t-2 (off-chain, from h2_{t-2}) ----
    float mh = dot8(m1p, h2a);
    mh += __shfl_xor(mh, 32, 64);
    float c = fmaxf(mh + mb1i, 0.0f) * mW2i;
    c += __shfl_xor(c, 1, 64);
    c += __shfl_xor(c, 2, 64);
    if (t >= 2) yc[(t - 2) * 8 + (i >> 2)] = c;   // quad-sum partials, 8/step

    // ---- bottom: refresh pipeline registers (latency covered by code above) ----
    __builtin_amdgcn_wave_barrier();
    d = yd[t + 1];                          // next step's dtime (unused garbage at t=n-1)
    ldlds(&hsh1[koff], h1a);                // h1_t
    ldlds(&hsh2[koff], h2a);                // h2_{t-1}
  }

  // ---------------- epilogue: drain the pipeline ----------------
  if (n >= 1) {
    // layer 2 step n-1 (h1a = h1_{n-1}, h2a = h2_{n-2})
    float br = dot8(u2r, h1a);
    float bz = dot8(u2z, h1a);
    float bn = dot8(u2n, h1a);
    float cr = dot8(w2r, h2a);
    float cz = dot8(w2z, h2a);
    float cn = dot8(w2n, h2a);
    br += __shfl_xor(br, 32, 64);
    bz += __shfl_xor(bz, 32, 64);
    bn += __shfl_xor(bn, 32, 64);
    cr += __shfl_xor(cr, 32, 64);
    cz += __shfl_xor(cz, 32, 64);
    cn += __shfl_xor(cn, 32, 64);
    float r2 = sigmoid_f(br + cr + c2r);
    float z2 = sigmoid_f(bz + cz + c2z);
    float n2 = tanh_f((bn + bih2n) + r2 * (cn + bhh2n));
    h2self = fmaf(z2, h2self - n2, n2);     // h2_{n-1}
    hsh2[i] = h2self;

    // MLP step n-2 from h2a = h2_{n-2}
    float mh = dot8(m1p, h2a);
    mh += __shfl_xor(mh, 32, 64);
    float c = fmaxf(mh + mb1i, 0.0f) * mW2i;
    c += __shfl_xor(c, 1, 64);
    c += __shfl_xor(c, 2, 64);
    if (n >= 2) yc[(n - 2) * 8 + (i >> 2)] = c;

    __builtin_amdgcn_wave_barrier();
    ldlds(&hsh2[koff], h2a);                // h2_{n-1}
  }
  {
    // final MLP: h2a = h2_{n-1} (or zeros when n==0) -> y_{n-1} and ylast
    float mh = dot8(m1p, h2a);
    mh += __shfl_xor(mh, 32, 64);
    float c = fmaxf(mh + mb1i, 0.0f) * mW2i;
    c += __shfl_xor(c, 1, 64);
    c += __shfl_xor(c, 2, 64);
    if (n >= 1) yc[(n - 1) * 8 + (i >> 2)] = c;
    yc[Tn * 8 + (i >> 2)] = c;              // ylast slot
  }
  __builtin_amdgcn_wave_barrier();

  // ---------------- batch reduce partials -> y, tail fill, store ----------------
  for (int t0 = 0; t0 < n; t0 += 64) {
    const int t = t0 + L;
    if (t < n) {
      float4 A  = *(const float4*)&yc[t * 8];
      float4 Bv = *(const float4*)&yc[t * 8 + 4];
      yd[t] = ((A.x + A.y) + (A.z + A.w)) + ((Bv.x + Bv.y) + (Bv.z + Bv.w)) + mb2v;
    }
  }
  float ylast;
  {
    float4 A  = *(const float4*)&yc[Tn * 8];
    float4 Bv = *(const float4*)&yc[Tn * 8 + 4];
    ylast = ((A.x + A.y) + (A.z + A.w)) + ((Bv.x + Bv.y) + (Bv.z + Bv.w)) + mb2v;
  }
  for (int t = n + L; t < Tn; t += 64) yd[t] = ylast;
  __builtin_amdgcn_wave_barrier();

  float* orow = out + (kb * Bn + b) * Tn;
  #pragma unroll
  for (int q = 0; q < 8; ++q) {
    const int idx = (q * 64 + L) * 4;
    float4 v = *(const float4*)&yd[idx];
    *(float4*)(orow + idx) = v;
  }
}

extern "C" void kernel_launch(void* const* d_in, const int* in_sizes, int n_in,
                              void* d_out, int out_size, void* d_ws, size_t ws_size,
                              hipStream_t stream) {
  const int*   band_ids = (const int*)  d_in[0];
  const float* dtime    = (const float*)d_in[1];
  const float* z_last   = (const float*)d_in[2];
  const float* projW    = (const float*)d_in[3];
  const float* projB    = (const float*)d_in[4];
  const float* Wih      = (const float*)d_in[5];
  const float* Whh      = (const float*)d_in[6];
  const float* bihp     = (const float*)d_in[7];
  const float* bhhp     = (const float*)d_in[8];
  const float* mW1      = (const float*)d_in[9];
  const float* mb1      = (const float*)d_in[10];
  const float* mW2      = (const float*)d_in[11];
  const float* mb2      = (const float*)d_in[12];
  float* out = (float*)d_out;
  rnn_decoder<<<dim3(Bn * 2), dim3(64), 0, stream>>>(
      band_ids, dtime, z_last, projW, projB, Wih, Whh, bihp, bhhp,
      mW1, mb1, mW2, mb2, out);
}